// Round 1
// baseline (251.687 us; speedup 1.0000x reference)
//
#include <hip/hip_runtime.h>
#include <cmath>

// ButterflyRotation: 12 layers of stride-2^l Givens rotations on rows of 4096 fp32.
// Fused single-pass kernel: 3 phases x 4 in-register layers, 2 LDS exchanges.
// cos/sin precomputed (permuted per-thread-slot) into d_ws by a tiny kernel.

namespace {
constexpr int kDim = 4096;
constexpr int kBatch = 8192;
constexpr int kLayers = 12;
constexpr int kPairs = kDim / 2;            // 2048
constexpr int kRowsPerBlock = 2;
constexpr int kThreads = 256;
// Pad 4 words per 64 so strided phase reads are exactly 2-way bank aliased
// (free) and b128 16B alignment is preserved (pad is a multiple of 4 words).
constexpr int kLdsWords = kDim + 4 * (kDim / 64);  // 4352
}

__device__ __forceinline__ int lds_pad(int i) { return i + ((i >> 6) << 2); }

// slot (l, t, q) -> original pair index p, shared by precompute + main kernel.
__device__ __forceinline__ int slot_to_pair(int l, int t, int q) {
    const int m = l & 3;
    const int phase = l >> 2;
    const int j = ((q >> m) << (m + 1)) | (q & ((1 << m) - 1));  // local left idx
    int i;
    if (phase == 0)      i = 16 * t + j;                          // strides 1..8
    else if (phase == 1) i = (t & 15) + 16 * j + 256 * (t >> 4);  // strides 16..128
    else                 i = t + 256 * j;                         // strides 256..2048
    const int s = 1 << l;
    return ((i >> (l + 1)) << l) | (i & (s - 1));                 // global pair idx
}

__global__ void bf_precompute_cs(const float* __restrict__ angles,
                                 float* __restrict__ cperm,
                                 float* __restrict__ sperm) {
    const int k = blockIdx.x * blockDim.x + threadIdx.x;
    if (k >= kLayers * kPairs) return;
    const int l = k >> 11;          // / 2048
    const int slot = k & 2047;
    const int t = slot >> 3;
    const int q = slot & 7;
    const int p = slot_to_pair(l, t, q);
    const float a = angles[l * kPairs + p];
    float sv, cv;
    sincosf(a, &sv, &cv);
    cperm[k] = cv;
    sperm[k] = sv;
}

template <int PHASE>
__device__ __forceinline__ void apply_phase(float (&v)[kRowsPerBlock][16], int t,
                                            const float* __restrict__ cperm,
                                            const float* __restrict__ sperm) {
#pragma unroll
    for (int m = 0; m < 4; ++m) {
        const int l = PHASE * 4 + m;
        const float4* cp = reinterpret_cast<const float4*>(cperm + l * kPairs + 8 * t);
        const float4* sp = reinterpret_cast<const float4*>(sperm + l * kPairs + 8 * t);
        const float4 c0 = cp[0], c1 = cp[1];
        const float4 s0 = sp[0], s1 = sp[1];
        const float c[8] = {c0.x, c0.y, c0.z, c0.w, c1.x, c1.y, c1.z, c1.w};
        const float s[8] = {s0.x, s0.y, s0.z, s0.w, s1.x, s1.y, s1.z, s1.w};
#pragma unroll
        for (int q = 0; q < 8; ++q) {
            const int j = ((q >> m) << (m + 1)) | (q & ((1 << m) - 1));
            const int jp = j + (1 << m);
#pragma unroll
            for (int r = 0; r < kRowsPerBlock; ++r) {
                const float xl = v[r][j], xr = v[r][jp];
                v[r][j]  = fmaf(xl, c[q],  xr * s[q]);   // new_left  =  xl*c + xr*s
                v[r][jp] = fmaf(xr, c[q], -xl * s[q]);   // new_right = -xl*s + xr*c
            }
        }
    }
}

__global__ __launch_bounds__(kThreads, 4)
void bf_butterfly(const float* __restrict__ x,
                  const float* __restrict__ cperm,
                  const float* __restrict__ sperm,
                  float* __restrict__ out) {
    __shared__ float lds[kRowsPerBlock][kLdsWords];
    const int t = threadIdx.x;
    const int row0 = blockIdx.x * kRowsPerBlock;

    float v[kRowsPerBlock][16];

    // ---- load: thread t owns contiguous elements [16t, 16t+16) of each row ----
#pragma unroll
    for (int r = 0; r < kRowsPerBlock; ++r) {
        const float4* src = reinterpret_cast<const float4*>(
            x + (size_t)(row0 + r) * kDim + 16 * t);
#pragma unroll
        for (int k = 0; k < 4; ++k) {
            const float4 f = src[k];
            v[r][4 * k + 0] = f.x; v[r][4 * k + 1] = f.y;
            v[r][4 * k + 2] = f.z; v[r][4 * k + 3] = f.w;
        }
    }

    // ---- phase 0: strides 1..8, in registers ----
    apply_phase<0>(v, t, cperm, sperm);

    // ---- exchange A: contiguous-16 layout -> {low + 16j + 256*high} layout ----
#pragma unroll
    for (int r = 0; r < kRowsPerBlock; ++r) {
#pragma unroll
        for (int k = 0; k < 4; ++k) {
            *reinterpret_cast<float4*>(&lds[r][lds_pad(16 * t + 4 * k)]) =
                make_float4(v[r][4 * k], v[r][4 * k + 1], v[r][4 * k + 2], v[r][4 * k + 3]);
        }
    }
    __syncthreads();
    const int low = t & 15, high = t >> 4;
#pragma unroll
    for (int r = 0; r < kRowsPerBlock; ++r) {
#pragma unroll
        for (int j = 0; j < 16; ++j) {
            v[r][j] = lds[r][lds_pad(low + 16 * j + 256 * high)];
        }
    }

    // ---- phase 1: strides 16..128, in registers ----
    apply_phase<1>(v, t, cperm, sperm);

    // ---- exchange B: -> {t + 256*j} layout ----
    __syncthreads();  // all exchange-A reads done before rewriting
#pragma unroll
    for (int r = 0; r < kRowsPerBlock; ++r) {
#pragma unroll
        for (int j = 0; j < 16; ++j) {
            lds[r][lds_pad(low + 16 * j + 256 * high)] = v[r][j];
        }
    }
    __syncthreads();
#pragma unroll
    for (int r = 0; r < kRowsPerBlock; ++r) {
#pragma unroll
        for (int j = 0; j < 16; ++j) {
            v[r][j] = lds[r][lds_pad(t + 256 * j)];
        }
    }

    // ---- phase 2: strides 256..2048, in registers ----
    apply_phase<2>(v, t, cperm, sperm);

    // ---- store: perfectly coalesced (lane t writes element t + 256j) ----
#pragma unroll
    for (int r = 0; r < kRowsPerBlock; ++r) {
        float* dst = out + (size_t)(row0 + r) * kDim;
#pragma unroll
        for (int j = 0; j < 16; ++j) {
            dst[t + 256 * j] = v[r][j];
        }
    }
}

extern "C" void kernel_launch(void* const* d_in, const int* in_sizes, int n_in,
                              void* d_out, int out_size, void* d_ws, size_t ws_size,
                              hipStream_t stream) {
    (void)in_sizes; (void)n_in; (void)out_size; (void)ws_size;
    const float* x = (const float*)d_in[0];
    const float* angles = (const float*)d_in[1];
    // d_in[2]/d_in[3] (left_idx/right_idx) are recomputed analytically.
    float* cperm = (float*)d_ws;                       // 12*2048 floats
    float* sperm = cperm + kLayers * kPairs;           // 12*2048 floats (192 KiB total)
    float* out = (float*)d_out;

    bf_precompute_cs<<<(kLayers * kPairs + kThreads - 1) / kThreads, kThreads, 0, stream>>>(
        angles, cperm, sperm);
    bf_butterfly<<<kBatch / kRowsPerBlock, kThreads, 0, stream>>>(x, cperm, sperm, out);
}